// Round 9
// baseline (171.354 us; speedup 1.0000x reference)
//
#include <hip/hip_runtime.h>

#define N_ATOMS 50000
#define N_BONDS 100000
#define BATCH   16
#define N3      150000   // N_ATOMS*3
#define BK      32       // bucket capacity per atom (Poisson(4): P(deg>32) ~ 1e-15)

// ---- fast-path workspace layout (4-byte element offsets) ----
#define X_OFF    0            // 4096 floats
#define MC_OFF   4096         // 16 floats (M 9, c 3)
#define CNT_OFF  4112         // 50000 ints (4112*4 % 16 == 0)
#define BKT_OFF  54112        // 50000*32 = 1,600,000 ints
#define HA_OFF   1654112      // 2,400,000 floats
#define HB_OFF   4054112      // 2,400,000 floats
#define WS_FAST_BYTES ((size_t)(HB_OFF + 2400000) * 4)   // ~25.8 MB

// ---- fallback layout ----
#define DEGF_OFF 4112         // 50000 floats
#define HT_OFF   54144        // 2,400,000 floats
#define NB_OFF   2454144      // 2,400,000 floats (optional in ws)

// ================= shared device helpers =================

// tiny MLP for batch b; all 256 threads of the block participate.
__device__ __forceinline__ void mlp_block(int b, int j,
    const float* __restrict__ alpha,
    const float* __restrict__ w_in, const float* __restrict__ b_in,
    const float* __restrict__ w1a, const float* __restrict__ b1a,
    const float* __restrict__ w1b, const float* __restrict__ b1b,
    const float* __restrict__ w2a, const float* __restrict__ b2a,
    const float* __restrict__ w2b, const float* __restrict__ b2b,
    float* xs, float* ts, float* __restrict__ x_out)
{
    float v = fmaxf(w_in[j] * alpha[b] + b_in[j], 0.f);
    xs[j] = v;
    __syncthreads();

    float acc = b1a[j];
    const float4* wr = reinterpret_cast<const float4*>(w1a + j * 256);
    #pragma unroll 8
    for (int k4 = 0; k4 < 64; ++k4) {
        float4 w = wr[k4];
        acc += w.x * xs[4*k4] + w.y * xs[4*k4+1] + w.z * xs[4*k4+2] + w.w * xs[4*k4+3];
    }
    ts[j] = fmaxf(acc, 0.f);
    __syncthreads();

    acc = b1b[j] + xs[j];
    wr = reinterpret_cast<const float4*>(w1b + j * 256);
    #pragma unroll 8
    for (int k4 = 0; k4 < 64; ++k4) {
        float4 w = wr[k4];
        acc += w.x * ts[4*k4] + w.y * ts[4*k4+1] + w.z * ts[4*k4+2] + w.w * ts[4*k4+3];
    }
    v = fmaxf(acc, 0.f);
    __syncthreads();
    xs[j] = v;
    __syncthreads();

    acc = b2a[j];
    wr = reinterpret_cast<const float4*>(w2a + j * 256);
    #pragma unroll 8
    for (int k4 = 0; k4 < 64; ++k4) {
        float4 w = wr[k4];
        acc += w.x * xs[4*k4] + w.y * xs[4*k4+1] + w.z * xs[4*k4+2] + w.w * xs[4*k4+3];
    }
    ts[j] = fmaxf(acc, 0.f);
    __syncthreads();

    acc = b2b[j] + xs[j];
    wr = reinterpret_cast<const float4*>(w2b + j * 256);
    #pragma unroll 8
    for (int k4 = 0; k4 < 64; ++k4) {
        float4 w = wr[k4];
        acc += w.x * ts[4*k4] + w.y * ts[4*k4+1] + w.z * ts[4*k4+2] + w.w * ts[4*k4+3];
    }
    x_out[b * 256 + j] = fmaxf(acc, 0.f);
}

// ================= K1: prep (MLP + mc + transpose + cnt-zero) =================
struct PrepParams {
    const float *alpha, *pos;
    const float *w_in, *b_in, *w1a, *b1a, *w1b, *b1b, *w2a, *b2a, *w2b, *b2b;
    const float *msg_w, *msg_b, *upd_w, *upd_b;
    float *x, *mc;
    int *cnt;
    float *hA;
};

__global__ __launch_bounds__(256) void prep_kernel(PrepParams p)
{
    __shared__ float smem[512];
    const int bid = blockIdx.x, tid = threadIdx.x;
    const int nb = gridDim.x;

    if (bid < 16) {
        mlp_block(bid, tid, p.alpha, p.w_in, p.b_in,
                  p.w1a, p.b1a, p.w1b, p.b1b, p.w2a, p.b2a, p.w2b, p.b2b,
                  smem, smem + 256, p.x);
    } else if (bid == 16) {
        if (tid < 9) {
            int d = tid / 3, dp = tid % 3;
            float s = 0.f;
            for (int k = 0; k < 128; ++k) s += p.upd_w[d*128 + k] * p.msg_w[k*3 + dp];
            p.mc[tid] = s;
        } else if (tid < 12) {
            int d = tid - 9;
            float s = p.upd_b[d];
            for (int k = 0; k < 128; ++k) s += p.upd_w[d*128 + k] * p.msg_b[k];
            p.mc[9 + d] = s;
        }
    } else {
        const int i0 = (bid - 17) * 256 + tid;
        const int st = (nb - 17) * 256;
        if (i0 < N_ATOMS / 4)
            ((int4*)p.cnt)[i0] = make_int4(0, 0, 0, 0);
        // transpose with coalesced READS: i indexes (b, n), n fastest.
        for (int i = i0; i < N_ATOMS * BATCH; i += st) {
            int b = i / N_ATOMS, n = i - b * N_ATOMS;
            const float* src = p.pos + ((size_t)b * N_ATOMS + n) * 3;
            float* dst = p.hA + n * 48 + b * 3;
            dst[0] = src[0]; dst[1] = src[1]; dst[2] = src[2];
        }
    }
}

// ================= K2: bucket fill (count + adjacency in one pass) =================
__global__ void fill_kernel(const int* __restrict__ bonds, int* __restrict__ cnt,
                            int* __restrict__ bucket)
{
    int e = blockIdx.x * blockDim.x + threadIdx.x;
    if (e >= N_BONDS) return;
    int a = bonds[2*e], b = bonds[2*e + 1];
    int sa = atomicAdd(cnt + a, 1);
    if (sa < BK) bucket[a * BK + sa] = b;
    int sb = atomicAdd(cnt + b, 1);
    if (sb < BK) bucket[b * BK + sb] = a;
}

// ============ K3/K4: bucket gather + mean + affine + residual ============
__global__ void gather_kernel(const int* __restrict__ cnt, const int* __restrict__ bucket,
                              const float* __restrict__ mc, const float* __restrict__ upd_b,
                              const float* __restrict__ h_in, float* __restrict__ h_out)
{
    int t = blockIdx.x * blockDim.x + threadIdx.x;
    if (t >= N_ATOMS * BATCH) return;
    int n = t >> 4, b = t & 15;
    int dg = cnt[n];
    int base = n * 48 + b * 3;
    float d0, d1, d2;
    if (dg > 0) {
        int m = dg > BK ? BK : dg;
        float s0 = 0.f, s1 = 0.f, s2 = 0.f;
        const int* bk = bucket + n * BK;
        for (int j = 0; j < m; ++j) {
            const float* hs = h_in + bk[j] * 48 + b * 3;
            s0 += hs[0]; s1 += hs[1]; s2 += hs[2];
        }
        float inv = 1.f / (float)dg;
        s0 *= inv; s1 *= inv; s2 *= inv;
        d0 = mc[9]  + mc[0]*s0 + mc[1]*s1 + mc[2]*s2;
        d1 = mc[10] + mc[3]*s0 + mc[4]*s1 + mc[5]*s2;
        d2 = mc[11] + mc[6]*s0 + mc[7]*s1 + mc[8]*s2;
    } else {
        d0 = upd_b[0]; d1 = upd_b[1]; d2 = upd_b[2];
    }
    h_out[base]     = h_in[base]     + d0;
    h_out[base + 1] = h_in[base + 1] + d1;
    h_out[base + 2] = h_in[base + 2] + d2;
}

// ---------------- K5: fused output GEMM + b_out + go-affine(h) ----------------
// Wave = 16 k-lanes x 4 b-lanes. Lane keeps its x-slice (4b x 16k = 64 floats)
// in registers; per row the 16 k-lanes read the 1KB w_out row fully coalesced
// (b-groups broadcast-merge). 4-step shfl_xor reduce over k; 16 writer lanes.
// 16 rows/wave -> 9375 waves: real TLP (vs 586 single-wave blocks before).
__global__ __launch_bounds__(256) void out_kernel(
    const float* __restrict__ w_out, const float* __restrict__ b_out,
    const float* __restrict__ x, const float* __restrict__ h_t,
    const float* __restrict__ go_w, const float* __restrict__ go_b,
    float* __restrict__ out)
{
    const int lane = threadIdx.x & 63;
    const int widx = threadIdx.x >> 6;
    const int wave_id = blockIdx.x * 4 + widx;
    const int b4 = lane >> 4;     // 0..3  (b-group: batches b4*4 .. b4*4+3)
    const int kk = lane & 15;     // 0..15 (k-slice: k = kk*16 .. kk*16+15)

    // x slice into registers: xr[bb][i] = x[(b4*4+bb)*256 + kk*16 + i*4 ..]
    float4 xr[4][4];
    #pragma unroll
    for (int bb = 0; bb < 4; ++bb)
        #pragma unroll
        for (int i = 0; i < 4; ++i)
            xr[bb][i] = *reinterpret_cast<const float4*>(
                x + (b4 * 4 + bb) * 256 + kk * 16 + i * 4);

    const int r0 = wave_id * 16;

    #pragma unroll 1
    for (int rr = 0; rr < 16; ++rr) {
        const int r = r0 + rr;
        if (r >= N3) break;                       // uniform per wave

        const float4* wrow = reinterpret_cast<const float4*>(w_out + (size_t)r * 256);
        float4 wv[4];
        #pragma unroll
        for (int i = 0; i < 4; ++i) wv[i] = wrow[kk * 4 + i];

        float acc[4] = {0.f, 0.f, 0.f, 0.f};
        #pragma unroll
        for (int i = 0; i < 4; ++i) {
            #pragma unroll
            for (int bb = 0; bb < 4; ++bb) {
                acc[bb] += wv[i].x * xr[bb][i].x + wv[i].y * xr[bb][i].y
                         + wv[i].z * xr[bb][i].z + wv[i].w * xr[bb][i].w;
            }
        }
        // reduce over the 16 k-lanes (xor masks stay within the 16-lane group)
        #pragma unroll
        for (int m = 1; m < 16; m <<= 1) {
            #pragma unroll
            for (int bb = 0; bb < 4; ++bb)
                acc[bb] += __shfl_xor(acc[bb], m);
        }
        // writer lanes: kk<4 writes batch b = b4*4 + kk (value acc[kk])
        if (kk < 4) {
            const int b = b4 * 4 + kk;
            const int n = r / 3, d = r - 3 * n;
            const float* hb = h_t + n * 48 + b * 3;
            float g = go_b[d] + b_out[r]
                    + go_w[d*3] * hb[0] + go_w[d*3 + 1] * hb[1] + go_w[d*3 + 2] * hb[2];
            out[(size_t)b * N3 + r] = acc[kk] + g;
        }
    }
}

// ================= fallback (small-ws) kernels: atomic scatter path =================
__global__ void zero4_kernel(int4* __restrict__ p, int n4)
{
    int t = blockIdx.x * 256 + threadIdx.x;
    if (t < n4) p[t] = make_int4(0, 0, 0, 0);
}

__global__ void mlp_head_kernel(const float* __restrict__ alpha,
    const float* __restrict__ w_in, const float* __restrict__ b_in,
    const float* __restrict__ w1a, const float* __restrict__ b1a,
    const float* __restrict__ w1b, const float* __restrict__ b1b,
    const float* __restrict__ w2a, const float* __restrict__ b2a,
    const float* __restrict__ w2b, const float* __restrict__ b2b,
    const float* __restrict__ msg_w, const float* __restrict__ msg_b,
    const float* __restrict__ upd_w, const float* __restrict__ upd_b,
    float* __restrict__ x_out, float* __restrict__ mc)
{
    const int b = blockIdx.x, j = threadIdx.x;
    if (b == 16) {
        if (j < 9) {
            int d = j / 3, dp = j % 3;
            float s = 0.f;
            for (int k = 0; k < 128; ++k) s += upd_w[d*128 + k] * msg_w[k*3 + dp];
            mc[j] = s;
        } else if (j < 12) {
            int d = j - 9;
            float s = upd_b[d];
            for (int k = 0; k < 128; ++k) s += upd_w[d*128 + k] * msg_b[k];
            mc[9 + d] = s;
        }
        return;
    }
    __shared__ float xs[256];
    __shared__ float ts[256];
    mlp_block(b, j, alpha, w_in, b_in, w1a, b1a, w1b, b1b, w2a, b2a, w2b, b2b,
              xs, ts, x_out);
}

__global__ void transpose_in_kernel(const float* __restrict__ pos, float* __restrict__ h_t)
{
    int t = blockIdx.x * blockDim.x + threadIdx.x;
    if (t >= N_ATOMS * 48) return;
    int n = t / 48, c = t % 48;
    int b = c / 3, d = c % 3;
    h_t[t] = pos[(b * N_ATOMS + n) * 3 + d];
}

__global__ void degf_kernel(const int* __restrict__ bonds, float* __restrict__ deg)
{
    int e = blockIdx.x * blockDim.x + threadIdx.x;
    if (e >= N_BONDS) return;
    atomicAdd(deg + bonds[2*e],     1.f);
    atomicAdd(deg + bonds[2*e + 1], 1.f);
}

__global__ void scatter_kernel(const int* __restrict__ bonds,
                               const float* __restrict__ h_t, float* __restrict__ nb_t)
{
    int t = blockIdx.x * 192 + threadIdx.x;
    int e = t / 48, c = t % 48;
    if (e >= N_BONDS) return;
    int a  = bonds[2*e];
    int bb = bonds[2*e + 1];
    float va = h_t[a  * 48 + c];
    float vb = h_t[bb * 48 + c];
    atomicAdd(nb_t + bb * 48 + c, va);
    atomicAdd(nb_t + a  * 48 + c, vb);
}

__global__ void update_kernel(const float* __restrict__ nb_t, const float* __restrict__ deg,
                              const float* __restrict__ mc, const float* __restrict__ upd_b,
                              float* __restrict__ h_t)
{
    int t = blockIdx.x * blockDim.x + threadIdx.x;
    if (t >= N_ATOMS * BATCH) return;
    int n = t >> 4;
    int base = n * 48 + (t & 15) * 3;
    float dg = deg[n];
    float d0, d1, d2;
    if (dg > 0.f) {
        float inv = 1.f / dg;
        float m0 = nb_t[base] * inv, m1 = nb_t[base+1] * inv, m2 = nb_t[base+2] * inv;
        d0 = mc[9]  + mc[0]*m0 + mc[1]*m1 + mc[2]*m2;
        d1 = mc[10] + mc[3]*m0 + mc[4]*m1 + mc[5]*m2;
        d2 = mc[11] + mc[6]*m0 + mc[7]*m1 + mc[8]*m2;
    } else {
        d0 = upd_b[0]; d1 = upd_b[1]; d2 = upd_b[2];
    }
    h_t[base]     += d0;
    h_t[base + 1] += d1;
    h_t[base + 2] += d2;
}

extern "C" void kernel_launch(void* const* d_in, const int* in_sizes, int n_in,
                              void* d_out, int out_size, void* d_ws, size_t ws_size,
                              hipStream_t stream)
{
    const float* alpha = (const float*)d_in[0];
    const float* pos   = (const float*)d_in[1];
    const int*   bonds = (const int*)  d_in[2];
    const float* w_in  = (const float*)d_in[3];
    const float* b_in  = (const float*)d_in[4];
    const float* w1a   = (const float*)d_in[5];
    const float* b1a   = (const float*)d_in[6];
    const float* w1b   = (const float*)d_in[7];
    const float* b1b   = (const float*)d_in[8];
    const float* w2a   = (const float*)d_in[9];
    const float* b2a   = (const float*)d_in[10];
    const float* w2b   = (const float*)d_in[11];
    const float* b2b   = (const float*)d_in[12];
    const float* w_out = (const float*)d_in[13];
    const float* b_out = (const float*)d_in[14];
    const float* msg_w = (const float*)d_in[15];
    const float* msg_b = (const float*)d_in[16];
    const float* upd_w = (const float*)d_in[17];
    const float* upd_b = (const float*)d_in[18];
    const float* go_w  = (const float*)d_in[19];
    const float* go_b  = (const float*)d_in[20];

    float* out = (float*)d_out;
    float* ws  = (float*)d_ws;
    float* x   = ws + X_OFF;
    float* mc  = ws + MC_OFF;

    float* h_final;
    if (ws_size >= WS_FAST_BYTES) {
        // -------- 5-dispatch full-occupancy fast path --------
        PrepParams pp;
        pp.alpha = alpha; pp.pos = pos;
        pp.w_in = w_in; pp.b_in = b_in;
        pp.w1a = w1a; pp.b1a = b1a; pp.w1b = w1b; pp.b1b = b1b;
        pp.w2a = w2a; pp.b2a = b2a; pp.w2b = w2b; pp.b2b = b2b;
        pp.msg_w = msg_w; pp.msg_b = msg_b; pp.upd_w = upd_w; pp.upd_b = upd_b;
        pp.x = x; pp.mc = mc;
        pp.cnt = (int*)(ws + CNT_OFF);
        pp.hA  = ws + HA_OFF;
        prep_kernel<<<1024, 256, 0, stream>>>(pp);

        int* cnt    = (int*)(ws + CNT_OFF);
        int* bucket = (int*)(ws + BKT_OFF);
        float* hA   = ws + HA_OFF;
        float* hB   = ws + HB_OFF;

        fill_kernel<<<(N_BONDS + 255) / 256, 256, 0, stream>>>(bonds, cnt, bucket);
        gather_kernel<<<(N_ATOMS * BATCH + 255) / 256, 256, 0, stream>>>(cnt, bucket, mc, upd_b, hA, hB);
        gather_kernel<<<(N_ATOMS * BATCH + 255) / 256, 256, 0, stream>>>(cnt, bucket, mc, upd_b, hB, hA);
        h_final = hA;
    } else {
        // -------- fallback: multi-dispatch atomic scatter path --------
        float* degf = ws + DEGF_OFF;
        float* h_t  = ws + HT_OFF;
        size_t need_full = (size_t)(NB_OFF + N_ATOMS * 48) * sizeof(float);
        float* nb_t = (ws_size >= need_full) ? (ws + NB_OFF) : out;

        mlp_head_kernel<<<17, 256, 0, stream>>>(alpha, w_in, b_in,
                                                w1a, b1a, w1b, b1b,
                                                w2a, b2a, w2b, b2b,
                                                msg_w, msg_b, upd_w, upd_b, x, mc);
        zero4_kernel<<<(N_ATOMS / 4 + 255) / 256, 256, 0, stream>>>((int4*)degf, N_ATOMS / 4);
        degf_kernel<<<(N_BONDS + 255) / 256, 256, 0, stream>>>(bonds, degf);
        transpose_in_kernel<<<(N_ATOMS * 48 + 255) / 256, 256, 0, stream>>>(pos, h_t);
        for (int it = 0; it < 2; ++it) {
            zero4_kernel<<<(N_ATOMS * 48 / 4 + 255) / 256, 256, 0, stream>>>((int4*)nb_t, N_ATOMS * 48 / 4);
            scatter_kernel<<<25000, 192, 0, stream>>>(bonds, h_t, nb_t);
            update_kernel<<<(N_ATOMS * BATCH + 255) / 256, 256, 0, stream>>>(nb_t, degf, mc, upd_b, h_t);
        }
        h_final = h_t;
    }

    // 9375 waves total: 2344 blocks x 4 waves, 16 rows per wave
    out_kernel<<<2344, 256, 0, stream>>>(w_out, b_out, x, h_final, go_w, go_b, out);
}

// Round 10
// 146.963 us; speedup vs baseline: 1.1660x; 1.1660x over previous
//
#include <hip/hip_runtime.h>

#define N_ATOMS 50000
#define N_BONDS 100000
#define BATCH   16
#define N3      150000   // N_ATOMS*3
#define BK      32       // bucket capacity per atom (Poisson(4): P(deg>32) ~ 1e-15)

// ---- fast-path workspace layout (4-byte element offsets) ----
#define X_OFF    0            // 4096 floats
#define MC_OFF   4096         // 16 floats (M 9, c 3)
#define CNT_OFF  4112         // 50000 ints (4112*4 % 16 == 0)
#define BKT_OFF  54112        // 50000*32 = 1,600,000 ints
#define HA_OFF   1654112      // 2,400,000 floats
#define HB_OFF   4054112      // 2,400,000 floats
#define WS_FAST_BYTES ((size_t)(HB_OFF + 2400000) * 4)   // ~25.8 MB

// ---- fallback layout ----
#define DEGF_OFF 4112         // 50000 floats
#define HT_OFF   54144        // 2,400,000 floats
#define NB_OFF   2454144      // 2,400,000 floats (optional in ws)

// ================= shared device helpers =================

// tiny MLP for batch b; all 256 threads of the block participate.
__device__ __forceinline__ void mlp_block(int b, int j,
    const float* __restrict__ alpha,
    const float* __restrict__ w_in, const float* __restrict__ b_in,
    const float* __restrict__ w1a, const float* __restrict__ b1a,
    const float* __restrict__ w1b, const float* __restrict__ b1b,
    const float* __restrict__ w2a, const float* __restrict__ b2a,
    const float* __restrict__ w2b, const float* __restrict__ b2b,
    float* xs, float* ts, float* __restrict__ x_out)
{
    float v = fmaxf(w_in[j] * alpha[b] + b_in[j], 0.f);
    xs[j] = v;
    __syncthreads();

    float acc = b1a[j];
    const float4* wr = reinterpret_cast<const float4*>(w1a + j * 256);
    #pragma unroll 8
    for (int k4 = 0; k4 < 64; ++k4) {
        float4 w = wr[k4];
        acc += w.x * xs[4*k4] + w.y * xs[4*k4+1] + w.z * xs[4*k4+2] + w.w * xs[4*k4+3];
    }
    ts[j] = fmaxf(acc, 0.f);
    __syncthreads();

    acc = b1b[j] + xs[j];
    wr = reinterpret_cast<const float4*>(w1b + j * 256);
    #pragma unroll 8
    for (int k4 = 0; k4 < 64; ++k4) {
        float4 w = wr[k4];
        acc += w.x * ts[4*k4] + w.y * ts[4*k4+1] + w.z * ts[4*k4+2] + w.w * ts[4*k4+3];
    }
    v = fmaxf(acc, 0.f);
    __syncthreads();
    xs[j] = v;
    __syncthreads();

    acc = b2a[j];
    wr = reinterpret_cast<const float4*>(w2a + j * 256);
    #pragma unroll 8
    for (int k4 = 0; k4 < 64; ++k4) {
        float4 w = wr[k4];
        acc += w.x * xs[4*k4] + w.y * xs[4*k4+1] + w.z * xs[4*k4+2] + w.w * xs[4*k4+3];
    }
    ts[j] = fmaxf(acc, 0.f);
    __syncthreads();

    acc = b2b[j] + xs[j];
    wr = reinterpret_cast<const float4*>(w2b + j * 256);
    #pragma unroll 8
    for (int k4 = 0; k4 < 64; ++k4) {
        float4 w = wr[k4];
        acc += w.x * ts[4*k4] + w.y * ts[4*k4+1] + w.z * ts[4*k4+2] + w.w * ts[4*k4+3];
    }
    x_out[b * 256 + j] = fmaxf(acc, 0.f);
}

// ================= K1: prep (MLP + mc + transpose + cnt-zero) =================
struct PrepParams {
    const float *alpha, *pos;
    const float *w_in, *b_in, *w1a, *b1a, *w1b, *b1b, *w2a, *b2a, *w2b, *b2b;
    const float *msg_w, *msg_b, *upd_w, *upd_b;
    float *x, *mc;
    int *cnt;
    float *hA;
};

__global__ __launch_bounds__(256) void prep_kernel(PrepParams p)
{
    __shared__ float smem[512];
    const int bid = blockIdx.x, tid = threadIdx.x;
    const int nb = gridDim.x;

    if (bid < 16) {
        mlp_block(bid, tid, p.alpha, p.w_in, p.b_in,
                  p.w1a, p.b1a, p.w1b, p.b1b, p.w2a, p.b2a, p.w2b, p.b2b,
                  smem, smem + 256, p.x);
    } else if (bid == 16) {
        if (tid < 9) {
            int d = tid / 3, dp = tid % 3;
            float s = 0.f;
            for (int k = 0; k < 128; ++k) s += p.upd_w[d*128 + k] * p.msg_w[k*3 + dp];
            p.mc[tid] = s;
        } else if (tid < 12) {
            int d = tid - 9;
            float s = p.upd_b[d];
            for (int k = 0; k < 128; ++k) s += p.upd_w[d*128 + k] * p.msg_b[k];
            p.mc[9 + d] = s;
        }
    } else {
        const int i0 = (bid - 17) * 256 + tid;
        const int st = (nb - 17) * 256;
        if (i0 < N_ATOMS / 4)
            ((int4*)p.cnt)[i0] = make_int4(0, 0, 0, 0);
        // transpose with coalesced READS: i indexes (b, n), n fastest.
        for (int i = i0; i < N_ATOMS * BATCH; i += st) {
            int b = i / N_ATOMS, n = i - b * N_ATOMS;
            const float* src = p.pos + ((size_t)b * N_ATOMS + n) * 3;
            float* dst = p.hA + n * 48 + b * 3;
            dst[0] = src[0]; dst[1] = src[1]; dst[2] = src[2];
        }
    }
}

// ================= K2: bucket fill (count + adjacency in one pass) =================
__global__ void fill_kernel(const int* __restrict__ bonds, int* __restrict__ cnt,
                            int* __restrict__ bucket)
{
    int e = blockIdx.x * blockDim.x + threadIdx.x;
    if (e >= N_BONDS) return;
    int a = bonds[2*e], b = bonds[2*e + 1];
    int sa = atomicAdd(cnt + a, 1);
    if (sa < BK) bucket[a * BK + sa] = b;
    int sb = atomicAdd(cnt + b, 1);
    if (sb < BK) bucket[b * BK + sb] = a;
}

// ============ K3/K4: bucket gather + mean + affine + residual ============
__global__ void gather_kernel(const int* __restrict__ cnt, const int* __restrict__ bucket,
                              const float* __restrict__ mc, const float* __restrict__ upd_b,
                              const float* __restrict__ h_in, float* __restrict__ h_out)
{
    int t = blockIdx.x * blockDim.x + threadIdx.x;
    if (t >= N_ATOMS * BATCH) return;
    int n = t >> 4, b = t & 15;
    int dg = cnt[n];
    int base = n * 48 + b * 3;
    float d0, d1, d2;
    if (dg > 0) {
        int m = dg > BK ? BK : dg;
        float s0 = 0.f, s1 = 0.f, s2 = 0.f;
        const int* bk = bucket + n * BK;
        for (int j = 0; j < m; ++j) {
            const float* hs = h_in + bk[j] * 48 + b * 3;
            s0 += hs[0]; s1 += hs[1]; s2 += hs[2];
        }
        float inv = 1.f / (float)dg;
        s0 *= inv; s1 *= inv; s2 *= inv;
        d0 = mc[9]  + mc[0]*s0 + mc[1]*s1 + mc[2]*s2;
        d1 = mc[10] + mc[3]*s0 + mc[4]*s1 + mc[5]*s2;
        d2 = mc[11] + mc[6]*s0 + mc[7]*s1 + mc[8]*s2;
    } else {
        d0 = upd_b[0]; d1 = upd_b[1]; d2 = upd_b[2];
    }
    h_out[base]     = h_in[base]     + d0;
    h_out[base + 1] = h_in[base + 1] + d1;
    h_out[base + 2] = h_in[base + 2] + d2;
}

// ---------------- K5: fused output GEMM + b_out + go-affine(h) ----------------
// Row-per-thread, NO LDS: x operand is wave-uniform -> scalar pipe (s_load,
// K-cache), zero VALU/LDS cost. w row register-prefetched 8 float4 deep:
// 8 coalesced loads in flight over 512 FMA cycles -> L3 latency hidden
// within-wave, so 2.3 waves/SIMD suffice. VALU floor ~7.8us chip-wide.
__global__ __launch_bounds__(256) void out_kernel(
    const float* __restrict__ w_out, const float* __restrict__ b_out,
    const float* __restrict__ x, const float* __restrict__ h_t,
    const float* __restrict__ go_w, const float* __restrict__ go_b,
    float* __restrict__ out)
{
    const int r = blockIdx.x * 256 + threadIdx.x;
    if (r >= N3) return;

    const float4* xv = reinterpret_cast<const float4*>(x);   // uniform -> s_load
    const float4* wr = reinterpret_cast<const float4*>(w_out + (size_t)r * 256);

    float acc[16];
    #pragma unroll
    for (int b = 0; b < 16; ++b) acc[b] = 0.f;

    float4 wbuf[8];
    #pragma unroll
    for (int i = 0; i < 8; ++i) wbuf[i] = wr[i];

    #pragma unroll 1
    for (int c = 0; c < 8; ++c) {
        float4 wcur[8];
        #pragma unroll
        for (int i = 0; i < 8; ++i) wcur[i] = wbuf[i];
        if (c < 7) {
            #pragma unroll
            for (int i = 0; i < 8; ++i) wbuf[i] = wr[(c + 1) * 8 + i];
        }
        #pragma unroll
        for (int i = 0; i < 8; ++i) {
            const int k4 = c * 8 + i;
            #pragma unroll
            for (int b = 0; b < 16; ++b) {
                float4 xf = xv[b * 64 + k4];     // wave-uniform scalar load
                acc[b] += wcur[i].x * xf.x + wcur[i].y * xf.y
                        + wcur[i].z * xf.z + wcur[i].w * xf.w;
            }
        }
    }

    const int n = r / 3, d = r - 3 * n;
    const float g0 = go_w[d*3], g1 = go_w[d*3 + 1], g2 = go_w[d*3 + 2];
    const float gb = go_b[d] + b_out[r];
    const float* hb = h_t + n * 48;
    #pragma unroll
    for (int b = 0; b < 16; ++b) {
        float g = gb + g0 * hb[b*3] + g1 * hb[b*3 + 1] + g2 * hb[b*3 + 2];
        out[(size_t)b * N3 + r] = acc[b] + g;
    }
}

// ================= fallback (small-ws) kernels: atomic scatter path =================
__global__ void zero4_kernel(int4* __restrict__ p, int n4)
{
    int t = blockIdx.x * 256 + threadIdx.x;
    if (t < n4) p[t] = make_int4(0, 0, 0, 0);
}

__global__ void mlp_head_kernel(const float* __restrict__ alpha,
    const float* __restrict__ w_in, const float* __restrict__ b_in,
    const float* __restrict__ w1a, const float* __restrict__ b1a,
    const float* __restrict__ w1b, const float* __restrict__ b1b,
    const float* __restrict__ w2a, const float* __restrict__ b2a,
    const float* __restrict__ w2b, const float* __restrict__ b2b,
    const float* __restrict__ msg_w, const float* __restrict__ msg_b,
    const float* __restrict__ upd_w, const float* __restrict__ upd_b,
    float* __restrict__ x_out, float* __restrict__ mc)
{
    const int b = blockIdx.x, j = threadIdx.x;
    if (b == 16) {
        if (j < 9) {
            int d = j / 3, dp = j % 3;
            float s = 0.f;
            for (int k = 0; k < 128; ++k) s += upd_w[d*128 + k] * msg_w[k*3 + dp];
            mc[j] = s;
        } else if (j < 12) {
            int d = j - 9;
            float s = upd_b[d];
            for (int k = 0; k < 128; ++k) s += upd_w[d*128 + k] * msg_b[k];
            mc[9 + d] = s;
        }
        return;
    }
    __shared__ float xs[256];
    __shared__ float ts[256];
    mlp_block(b, j, alpha, w_in, b_in, w1a, b1a, w1b, b1b, w2a, b2a, w2b, b2b,
              xs, ts, x_out);
}

__global__ void transpose_in_kernel(const float* __restrict__ pos, float* __restrict__ h_t)
{
    int t = blockIdx.x * blockDim.x + threadIdx.x;
    if (t >= N_ATOMS * 48) return;
    int n = t / 48, c = t % 48;
    int b = c / 3, d = c % 3;
    h_t[t] = pos[(b * N_ATOMS + n) * 3 + d];
}

__global__ void degf_kernel(const int* __restrict__ bonds, float* __restrict__ deg)
{
    int e = blockIdx.x * blockDim.x + threadIdx.x;
    if (e >= N_BONDS) return;
    atomicAdd(deg + bonds[2*e],     1.f);
    atomicAdd(deg + bonds[2*e + 1], 1.f);
}

__global__ void scatter_kernel(const int* __restrict__ bonds,
                               const float* __restrict__ h_t, float* __restrict__ nb_t)
{
    int t = blockIdx.x * 192 + threadIdx.x;
    int e = t / 48, c = t % 48;
    if (e >= N_BONDS) return;
    int a  = bonds[2*e];
    int bb = bonds[2*e + 1];
    float va = h_t[a  * 48 + c];
    float vb = h_t[bb * 48 + c];
    atomicAdd(nb_t + bb * 48 + c, va);
    atomicAdd(nb_t + a  * 48 + c, vb);
}

__global__ void update_kernel(const float* __restrict__ nb_t, const float* __restrict__ deg,
                              const float* __restrict__ mc, const float* __restrict__ upd_b,
                              float* __restrict__ h_t)
{
    int t = blockIdx.x * blockDim.x + threadIdx.x;
    if (t >= N_ATOMS * BATCH) return;
    int n = t >> 4;
    int base = n * 48 + (t & 15) * 3;
    float dg = deg[n];
    float d0, d1, d2;
    if (dg > 0.f) {
        float inv = 1.f / dg;
        float m0 = nb_t[base] * inv, m1 = nb_t[base+1] * inv, m2 = nb_t[base+2] * inv;
        d0 = mc[9]  + mc[0]*m0 + mc[1]*m1 + mc[2]*m2;
        d1 = mc[10] + mc[3]*m0 + mc[4]*m1 + mc[5]*m2;
        d2 = mc[11] + mc[6]*m0 + mc[7]*m1 + mc[8]*m2;
    } else {
        d0 = upd_b[0]; d1 = upd_b[1]; d2 = upd_b[2];
    }
    h_t[base]     += d0;
    h_t[base + 1] += d1;
    h_t[base + 2] += d2;
}

extern "C" void kernel_launch(void* const* d_in, const int* in_sizes, int n_in,
                              void* d_out, int out_size, void* d_ws, size_t ws_size,
                              hipStream_t stream)
{
    const float* alpha = (const float*)d_in[0];
    const float* pos   = (const float*)d_in[1];
    const int*   bonds = (const int*)  d_in[2];
    const float* w_in  = (const float*)d_in[3];
    const float* b_in  = (const float*)d_in[4];
    const float* w1a   = (const float*)d_in[5];
    const float* b1a   = (const float*)d_in[6];
    const float* w1b   = (const float*)d_in[7];
    const float* b1b   = (const float*)d_in[8];
    const float* w2a   = (const float*)d_in[9];
    const float* b2a   = (const float*)d_in[10];
    const float* w2b   = (const float*)d_in[11];
    const float* b2b   = (const float*)d_in[12];
    const float* w_out = (const float*)d_in[13];
    const float* b_out = (const float*)d_in[14];
    const float* msg_w = (const float*)d_in[15];
    const float* msg_b = (const float*)d_in[16];
    const float* upd_w = (const float*)d_in[17];
    const float* upd_b = (const float*)d_in[18];
    const float* go_w  = (const float*)d_in[19];
    const float* go_b  = (const float*)d_in[20];

    float* out = (float*)d_out;
    float* ws  = (float*)d_ws;
    float* x   = ws + X_OFF;
    float* mc  = ws + MC_OFF;

    float* h_final;
    if (ws_size >= WS_FAST_BYTES) {
        // -------- 5-dispatch full-occupancy fast path --------
        PrepParams pp;
        pp.alpha = alpha; pp.pos = pos;
        pp.w_in = w_in; pp.b_in = b_in;
        pp.w1a = w1a; pp.b1a = b1a; pp.w1b = w1b; pp.b1b = b1b;
        pp.w2a = w2a; pp.b2a = b2a; pp.w2b = w2b; pp.b2b = b2b;
        pp.msg_w = msg_w; pp.msg_b = msg_b; pp.upd_w = upd_w; pp.upd_b = upd_b;
        pp.x = x; pp.mc = mc;
        pp.cnt = (int*)(ws + CNT_OFF);
        pp.hA  = ws + HA_OFF;
        prep_kernel<<<1024, 256, 0, stream>>>(pp);

        int* cnt    = (int*)(ws + CNT_OFF);
        int* bucket = (int*)(ws + BKT_OFF);
        float* hA   = ws + HA_OFF;
        float* hB   = ws + HB_OFF;

        fill_kernel<<<(N_BONDS + 255) / 256, 256, 0, stream>>>(bonds, cnt, bucket);
        gather_kernel<<<(N_ATOMS * BATCH + 255) / 256, 256, 0, stream>>>(cnt, bucket, mc, upd_b, hA, hB);
        gather_kernel<<<(N_ATOMS * BATCH + 255) / 256, 256, 0, stream>>>(cnt, bucket, mc, upd_b, hB, hA);
        h_final = hA;
    } else {
        // -------- fallback: multi-dispatch atomic scatter path --------
        float* degf = ws + DEGF_OFF;
        float* h_t  = ws + HT_OFF;
        size_t need_full = (size_t)(NB_OFF + N_ATOMS * 48) * sizeof(float);
        float* nb_t = (ws_size >= need_full) ? (ws + NB_OFF) : out;

        mlp_head_kernel<<<17, 256, 0, stream>>>(alpha, w_in, b_in,
                                                w1a, b1a, w1b, b1b,
                                                w2a, b2a, w2b, b2b,
                                                msg_w, msg_b, upd_w, upd_b, x, mc);
        zero4_kernel<<<(N_ATOMS / 4 + 255) / 256, 256, 0, stream>>>((int4*)degf, N_ATOMS / 4);
        degf_kernel<<<(N_BONDS + 255) / 256, 256, 0, stream>>>(bonds, degf);
        transpose_in_kernel<<<(N_ATOMS * 48 + 255) / 256, 256, 0, stream>>>(pos, h_t);
        for (int it = 0; it < 2; ++it) {
            zero4_kernel<<<(N_ATOMS * 48 / 4 + 255) / 256, 256, 0, stream>>>((int4*)nb_t, N_ATOMS * 48 / 4);
            scatter_kernel<<<25000, 192, 0, stream>>>(bonds, h_t, nb_t);
            update_kernel<<<(N_ATOMS * BATCH + 255) / 256, 256, 0, stream>>>(nb_t, degf, mc, upd_b, h_t);
        }
        h_final = h_t;
    }

    out_kernel<<<(N3 + 255) / 256, 256, 0, stream>>>(w_out, b_out, x, h_final, go_w, go_b, out);
}

// Round 11
// 134.047 us; speedup vs baseline: 1.2783x; 1.0964x over previous
//
#include <hip/hip_runtime.h>

#define N_ATOMS 50000
#define N_BONDS 100000
#define BATCH   16
#define N3      150000   // N_ATOMS*3
#define BK      32       // bucket capacity per atom (Poisson(4): P(deg>32) ~ 1e-15)

// ---- fast-path workspace layout (4-byte element offsets) ----
#define X_OFF    0            // 4096 floats
#define MC_OFF   4096         // 16 floats (M 9, c 3)
#define CNT_OFF  4112         // 50000 ints (4112*4 % 16 == 0)
#define BKT_OFF  54112        // 50000*32 = 1,600,000 ints
#define HA_OFF   1654112      // 2,400,000 floats
#define HB_OFF   4054112      // 2,400,000 floats
#define WS_FAST_BYTES ((size_t)(HB_OFF + 2400000) * 4)   // ~25.8 MB

// ---- fallback layout ----
#define DEGF_OFF 4112         // 50000 floats
#define HT_OFF   54144        // 2,400,000 floats
#define NB_OFF   2454144      // 2,400,000 floats (optional in ws)

// ================= shared device helpers =================

// tiny MLP for batch b; all 256 threads of the block participate.
__device__ __forceinline__ void mlp_block(int b, int j,
    const float* __restrict__ alpha,
    const float* __restrict__ w_in, const float* __restrict__ b_in,
    const float* __restrict__ w1a, const float* __restrict__ b1a,
    const float* __restrict__ w1b, const float* __restrict__ b1b,
    const float* __restrict__ w2a, const float* __restrict__ b2a,
    const float* __restrict__ w2b, const float* __restrict__ b2b,
    float* xs, float* ts, float* __restrict__ x_out)
{
    float v = fmaxf(w_in[j] * alpha[b] + b_in[j], 0.f);
    xs[j] = v;
    __syncthreads();

    float acc = b1a[j];
    const float4* wr = reinterpret_cast<const float4*>(w1a + j * 256);
    #pragma unroll 8
    for (int k4 = 0; k4 < 64; ++k4) {
        float4 w = wr[k4];
        acc += w.x * xs[4*k4] + w.y * xs[4*k4+1] + w.z * xs[4*k4+2] + w.w * xs[4*k4+3];
    }
    ts[j] = fmaxf(acc, 0.f);
    __syncthreads();

    acc = b1b[j] + xs[j];
    wr = reinterpret_cast<const float4*>(w1b + j * 256);
    #pragma unroll 8
    for (int k4 = 0; k4 < 64; ++k4) {
        float4 w = wr[k4];
        acc += w.x * ts[4*k4] + w.y * ts[4*k4+1] + w.z * ts[4*k4+2] + w.w * ts[4*k4+3];
    }
    v = fmaxf(acc, 0.f);
    __syncthreads();
    xs[j] = v;
    __syncthreads();

    acc = b2a[j];
    wr = reinterpret_cast<const float4*>(w2a + j * 256);
    #pragma unroll 8
    for (int k4 = 0; k4 < 64; ++k4) {
        float4 w = wr[k4];
        acc += w.x * xs[4*k4] + w.y * xs[4*k4+1] + w.z * xs[4*k4+2] + w.w * xs[4*k4+3];
    }
    ts[j] = fmaxf(acc, 0.f);
    __syncthreads();

    acc = b2b[j] + xs[j];
    wr = reinterpret_cast<const float4*>(w2b + j * 256);
    #pragma unroll 8
    for (int k4 = 0; k4 < 64; ++k4) {
        float4 w = wr[k4];
        acc += w.x * ts[4*k4] + w.y * ts[4*k4+1] + w.z * ts[4*k4+2] + w.w * ts[4*k4+3];
    }
    x_out[b * 256 + j] = fmaxf(acc, 0.f);
}

// ================= K1: prep (MLP + mc + transpose + cnt-zero) =================
// Transpose uses R7's proven mapping: coalesced WRITES to h (t contiguous),
// 12B-granular scattered reads of pos (L2-cached). The R8 "coalesced-read"
// variant scattered 4B writes at 192B stride across blocks -> partial-line
// write-allocate traffic, ~15-20us regression. Do not flip back.
struct PrepParams {
    const float *alpha, *pos;
    const float *w_in, *b_in, *w1a, *b1a, *w1b, *b1b, *w2a, *b2a, *w2b, *b2b;
    const float *msg_w, *msg_b, *upd_w, *upd_b;
    float *x, *mc;
    int *cnt;
    float *hA;
};

__global__ __launch_bounds__(256) void prep_kernel(PrepParams p)
{
    __shared__ float smem[512];
    const int bid = blockIdx.x, tid = threadIdx.x;
    const int nb = gridDim.x;

    if (bid < 16) {
        mlp_block(bid, tid, p.alpha, p.w_in, p.b_in,
                  p.w1a, p.b1a, p.w1b, p.b1b, p.w2a, p.b2a, p.w2b, p.b2b,
                  smem, smem + 256, p.x);
    } else if (bid == 16) {
        if (tid < 9) {
            int d = tid / 3, dp = tid % 3;
            float s = 0.f;
            for (int k = 0; k < 128; ++k) s += p.upd_w[d*128 + k] * p.msg_w[k*3 + dp];
            p.mc[tid] = s;
        } else if (tid < 12) {
            int d = tid - 9;
            float s = p.upd_b[d];
            for (int k = 0; k < 128; ++k) s += p.upd_w[d*128 + k] * p.msg_b[k];
            p.mc[9 + d] = s;
        }
    } else {
        const int i0 = (bid - 17) * 256 + tid;
        const int st = (nb - 17) * 256;
        if (i0 < N_ATOMS / 4)
            ((int4*)p.cnt)[i0] = make_int4(0, 0, 0, 0);
        for (int i = i0; i < N_ATOMS * 48; i += st) {
            int n = i / 48, c = i - n * 48;
            int b = c / 3, d = c - b * 3;
            p.hA[i] = p.pos[(b * N_ATOMS + n) * 3 + d];
        }
    }
}

// ================= K2: bucket fill (count + adjacency in one pass) =================
__global__ void fill_kernel(const int* __restrict__ bonds, int* __restrict__ cnt,
                            int* __restrict__ bucket)
{
    int e = blockIdx.x * blockDim.x + threadIdx.x;
    if (e >= N_BONDS) return;
    int a = bonds[2*e], b = bonds[2*e + 1];
    int sa = atomicAdd(cnt + a, 1);
    if (sa < BK) bucket[a * BK + sa] = b;
    int sb = atomicAdd(cnt + b, 1);
    if (sb < BK) bucket[b * BK + sb] = a;
}

// ============ K3/K4: bucket gather + mean + affine + residual ============
__global__ void gather_kernel(const int* __restrict__ cnt, const int* __restrict__ bucket,
                              const float* __restrict__ mc, const float* __restrict__ upd_b,
                              const float* __restrict__ h_in, float* __restrict__ h_out)
{
    int t = blockIdx.x * blockDim.x + threadIdx.x;
    if (t >= N_ATOMS * BATCH) return;
    int n = t >> 4, b = t & 15;
    int dg = cnt[n];
    int base = n * 48 + b * 3;
    float d0, d1, d2;
    if (dg > 0) {
        int m = dg > BK ? BK : dg;
        float s0 = 0.f, s1 = 0.f, s2 = 0.f;
        const int* bk = bucket + n * BK;
        for (int j = 0; j < m; ++j) {
            const float* hs = h_in + bk[j] * 48 + b * 3;
            s0 += hs[0]; s1 += hs[1]; s2 += hs[2];
        }
        float inv = 1.f / (float)dg;
        s0 *= inv; s1 *= inv; s2 *= inv;
        d0 = mc[9]  + mc[0]*s0 + mc[1]*s1 + mc[2]*s2;
        d1 = mc[10] + mc[3]*s0 + mc[4]*s1 + mc[5]*s2;
        d2 = mc[11] + mc[6]*s0 + mc[7]*s1 + mc[8]*s2;
    } else {
        d0 = upd_b[0]; d1 = upd_b[1]; d2 = upd_b[2];
    }
    h_out[base]     = h_in[base]     + d0;
    h_out[base + 1] = h_in[base + 1] + d1;
    h_out[base + 2] = h_in[base + 2] + d2;
}

// ---------------- K5: fused output GEMM + b_out + go-affine(h) ----------------
// R7's proven 2-row double-buffered structure, but 256-thread blocks:
// 4 waves share one 16KB xs -> LDS/wave drops 4x, occupancy ~10 -> ~20
// waves/CU (VGPR-bound), doubling latency-hiding TLP. 293 blocks.
__global__ __launch_bounds__(256) void out_kernel(
    const float* __restrict__ w_out, const float* __restrict__ b_out,
    const float* __restrict__ x, const float* __restrict__ h_t,
    const float* __restrict__ go_w, const float* __restrict__ go_b,
    float* __restrict__ out)
{
    __shared__ float4 xs[1024];                 // [b][k4], 16 KiB shared by 4 waves
    const int tid = threadIdx.x;
    const float4* xv = reinterpret_cast<const float4*>(x);
    #pragma unroll
    for (int i = 0; i < 4; ++i) xs[tid + i * 256] = xv[tid + i * 256];
    __syncthreads();

    const int r0 = blockIdx.x * 512 + tid;
    const int r1 = r0 + 256;
    const bool v0 = (r0 < N3);
    const bool v1 = (r1 < N3);
    const int r0c = v0 ? r0 : 0;
    const int r1c = v1 ? r1 : 0;

    const float4* wr0 = reinterpret_cast<const float4*>(w_out + (size_t)r0c * 256);
    const float4* wr1 = reinterpret_cast<const float4*>(w_out + (size_t)r1c * 256);

    float acc0[16], acc1[16];
    #pragma unroll
    for (int b = 0; b < 16; ++b) { acc0[b] = 0.f; acc1[b] = 0.f; }

    float4 wbuf0[4], wbuf1[4];
    #pragma unroll
    for (int i = 0; i < 4; ++i) { wbuf0[i] = wr0[i]; wbuf1[i] = wr1[i]; }

    #pragma unroll 1
    for (int c = 0; c < 16; ++c) {
        float4 wc0[4], wc1[4];
        #pragma unroll
        for (int i = 0; i < 4; ++i) { wc0[i] = wbuf0[i]; wc1[i] = wbuf1[i]; }
        if (c < 15) {
            #pragma unroll
            for (int i = 0; i < 4; ++i) {
                wbuf0[i] = wr0[(c + 1) * 4 + i];
                wbuf1[i] = wr1[(c + 1) * 4 + i];
            }
        }
        #pragma unroll
        for (int i = 0; i < 4; ++i) {
            const int k4 = c * 4 + i;
            #pragma unroll
            for (int b = 0; b < 16; ++b) {
                float4 xf = xs[b * 64 + k4];
                acc0[b] += wc0[i].x * xf.x + wc0[i].y * xf.y
                         + wc0[i].z * xf.z + wc0[i].w * xf.w;
                acc1[b] += wc1[i].x * xf.x + wc1[i].y * xf.y
                         + wc1[i].z * xf.z + wc1[i].w * xf.w;
            }
        }
    }

    if (v0) {
        const int n = r0 / 3, d = r0 - 3 * n;
        const float g0 = go_w[d*3], g1 = go_w[d*3 + 1], g2 = go_w[d*3 + 2];
        const float gb = go_b[d] + b_out[r0];
        const float* hb = h_t + n * 48;
        #pragma unroll
        for (int b = 0; b < 16; ++b) {
            float g = gb + g0 * hb[b*3] + g1 * hb[b*3 + 1] + g2 * hb[b*3 + 2];
            out[(size_t)b * N3 + r0] = acc0[b] + g;
        }
    }
    if (v1) {
        const int n = r1 / 3, d = r1 - 3 * n;
        const float g0 = go_w[d*3], g1 = go_w[d*3 + 1], g2 = go_w[d*3 + 2];
        const float gb = go_b[d] + b_out[r1];
        const float* hb = h_t + n * 48;
        #pragma unroll
        for (int b = 0; b < 16; ++b) {
            float g = gb + g0 * hb[b*3] + g1 * hb[b*3 + 1] + g2 * hb[b*3 + 2];
            out[(size_t)b * N3 + r1] = acc1[b] + g;
        }
    }
}

// ================= fallback (small-ws) kernels: atomic scatter path =================
__global__ void zero4_kernel(int4* __restrict__ p, int n4)
{
    int t = blockIdx.x * 256 + threadIdx.x;
    if (t < n4) p[t] = make_int4(0, 0, 0, 0);
}

__global__ void mlp_head_kernel(const float* __restrict__ alpha,
    const float* __restrict__ w_in, const float* __restrict__ b_in,
    const float* __restrict__ w1a, const float* __restrict__ b1a,
    const float* __restrict__ w1b, const float* __restrict__ b1b,
    const float* __restrict__ w2a, const float* __restrict__ b2a,
    const float* __restrict__ w2b, const float* __restrict__ b2b,
    const float* __restrict__ msg_w, const float* __restrict__ msg_b,
    const float* __restrict__ upd_w, const float* __restrict__ upd_b,
    float* __restrict__ x_out, float* __restrict__ mc)
{
    const int b = blockIdx.x, j = threadIdx.x;
    if (b == 16) {
        if (j < 9) {
            int d = j / 3, dp = j % 3;
            float s = 0.f;
            for (int k = 0; k < 128; ++k) s += upd_w[d*128 + k] * msg_w[k*3 + dp];
            mc[j] = s;
        } else if (j < 12) {
            int d = j - 9;
            float s = upd_b[d];
            for (int k = 0; k < 128; ++k) s += upd_w[d*128 + k] * msg_b[k];
            mc[9 + d] = s;
        }
        return;
    }
    __shared__ float xs[256];
    __shared__ float ts[256];
    mlp_block(b, j, alpha, w_in, b_in, w1a, b1a, w1b, b1b, w2a, b2a, w2b, b2b,
              xs, ts, x_out);
}

__global__ void transpose_in_kernel(const float* __restrict__ pos, float* __restrict__ h_t)
{
    int t = blockIdx.x * blockDim.x + threadIdx.x;
    if (t >= N_ATOMS * 48) return;
    int n = t / 48, c = t % 48;
    int b = c / 3, d = c % 3;
    h_t[t] = pos[(b * N_ATOMS + n) * 3 + d];
}

__global__ void degf_kernel(const int* __restrict__ bonds, float* __restrict__ deg)
{
    int e = blockIdx.x * blockDim.x + threadIdx.x;
    if (e >= N_BONDS) return;
    atomicAdd(deg + bonds[2*e],     1.f);
    atomicAdd(deg + bonds[2*e + 1], 1.f);
}

__global__ void scatter_kernel(const int* __restrict__ bonds,
                               const float* __restrict__ h_t, float* __restrict__ nb_t)
{
    int t = blockIdx.x * 192 + threadIdx.x;
    int e = t / 48, c = t % 48;
    if (e >= N_BONDS) return;
    int a  = bonds[2*e];
    int bb = bonds[2*e + 1];
    float va = h_t[a  * 48 + c];
    float vb = h_t[bb * 48 + c];
    atomicAdd(nb_t + bb * 48 + c, va);
    atomicAdd(nb_t + a  * 48 + c, vb);
}

__global__ void update_kernel(const float* __restrict__ nb_t, const float* __restrict__ deg,
                              const float* __restrict__ mc, const float* __restrict__ upd_b,
                              float* __restrict__ h_t)
{
    int t = blockIdx.x * blockDim.x + threadIdx.x;
    if (t >= N_ATOMS * BATCH) return;
    int n = t >> 4;
    int base = n * 48 + (t & 15) * 3;
    float dg = deg[n];
    float d0, d1, d2;
    if (dg > 0.f) {
        float inv = 1.f / dg;
        float m0 = nb_t[base] * inv, m1 = nb_t[base+1] * inv, m2 = nb_t[base+2] * inv;
        d0 = mc[9]  + mc[0]*m0 + mc[1]*m1 + mc[2]*m2;
        d1 = mc[10] + mc[3]*m0 + mc[4]*m1 + mc[5]*m2;
        d2 = mc[11] + mc[6]*m0 + mc[7]*m1 + mc[8]*m2;
    } else {
        d0 = upd_b[0]; d1 = upd_b[1]; d2 = upd_b[2];
    }
    h_t[base]     += d0;
    h_t[base + 1] += d1;
    h_t[base + 2] += d2;
}

extern "C" void kernel_launch(void* const* d_in, const int* in_sizes, int n_in,
                              void* d_out, int out_size, void* d_ws, size_t ws_size,
                              hipStream_t stream)
{
    const float* alpha = (const float*)d_in[0];
    const float* pos   = (const float*)d_in[1];
    const int*   bonds = (const int*)  d_in[2];
    const float* w_in  = (const float*)d_in[3];
    const float* b_in  = (const float*)d_in[4];
    const float* w1a   = (const float*)d_in[5];
    const float* b1a   = (const float*)d_in[6];
    const float* w1b   = (const float*)d_in[7];
    const float* b1b   = (const float*)d_in[8];
    const float* w2a   = (const float*)d_in[9];
    const float* b2a   = (const float*)d_in[10];
    const float* w2b   = (const float*)d_in[11];
    const float* b2b   = (const float*)d_in[12];
    const float* w_out = (const float*)d_in[13];
    const float* b_out = (const float*)d_in[14];
    const float* msg_w = (const float*)d_in[15];
    const float* msg_b = (const float*)d_in[16];
    const float* upd_w = (const float*)d_in[17];
    const float* upd_b = (const float*)d_in[18];
    const float* go_w  = (const float*)d_in[19];
    const float* go_b  = (const float*)d_in[20];

    float* out = (float*)d_out;
    float* ws  = (float*)d_ws;
    float* x   = ws + X_OFF;
    float* mc  = ws + MC_OFF;

    float* h_final;
    if (ws_size >= WS_FAST_BYTES) {
        // -------- 5-dispatch full-occupancy fast path --------
        PrepParams pp;
        pp.alpha = alpha; pp.pos = pos;
        pp.w_in = w_in; pp.b_in = b_in;
        pp.w1a = w1a; pp.b1a = b1a; pp.w1b = w1b; pp.b1b = b1b;
        pp.w2a = w2a; pp.b2a = b2a; pp.w2b = w2b; pp.b2b = b2b;
        pp.msg_w = msg_w; pp.msg_b = msg_b; pp.upd_w = upd_w; pp.upd_b = upd_b;
        pp.x = x; pp.mc = mc;
        pp.cnt = (int*)(ws + CNT_OFF);
        pp.hA  = ws + HA_OFF;
        prep_kernel<<<1024, 256, 0, stream>>>(pp);

        int* cnt    = (int*)(ws + CNT_OFF);
        int* bucket = (int*)(ws + BKT_OFF);
        float* hA   = ws + HA_OFF;
        float* hB   = ws + HB_OFF;

        fill_kernel<<<(N_BONDS + 255) / 256, 256, 0, stream>>>(bonds, cnt, bucket);
        gather_kernel<<<(N_ATOMS * BATCH + 255) / 256, 256, 0, stream>>>(cnt, bucket, mc, upd_b, hA, hB);
        gather_kernel<<<(N_ATOMS * BATCH + 255) / 256, 256, 0, stream>>>(cnt, bucket, mc, upd_b, hB, hA);
        h_final = hA;
    } else {
        // -------- fallback: multi-dispatch atomic scatter path --------
        float* degf = ws + DEGF_OFF;
        float* h_t  = ws + HT_OFF;
        size_t need_full = (size_t)(NB_OFF + N_ATOMS * 48) * sizeof(float);
        float* nb_t = (ws_size >= need_full) ? (ws + NB_OFF) : out;

        mlp_head_kernel<<<17, 256, 0, stream>>>(alpha, w_in, b_in,
                                                w1a, b1a, w1b, b1b,
                                                w2a, b2a, w2b, b2b,
                                                msg_w, msg_b, upd_w, upd_b, x, mc);
        zero4_kernel<<<(N_ATOMS / 4 + 255) / 256, 256, 0, stream>>>((int4*)degf, N_ATOMS / 4);
        degf_kernel<<<(N_BONDS + 255) / 256, 256, 0, stream>>>(bonds, degf);
        transpose_in_kernel<<<(N_ATOMS * 48 + 255) / 256, 256, 0, stream>>>(pos, h_t);
        for (int it = 0; it < 2; ++it) {
            zero4_kernel<<<(N_ATOMS * 48 / 4 + 255) / 256, 256, 0, stream>>>((int4*)nb_t, N_ATOMS * 48 / 4);
            scatter_kernel<<<25000, 192, 0, stream>>>(bonds, h_t, nb_t);
            update_kernel<<<(N_ATOMS * BATCH + 255) / 256, 256, 0, stream>>>(nb_t, degf, mc, upd_b, h_t);
        }
        h_final = h_t;
    }

    // 293 blocks x 256 threads; 2 rows/thread (512 rows/block)
    out_kernel<<<(N3 + 511) / 512, 256, 0, stream>>>(w_out, b_out, x, h_final, go_w, go_b, out);
}

// Round 13
// 133.126 us; speedup vs baseline: 1.2872x; 1.0069x over previous
//
#include <hip/hip_runtime.h>

#define N_ATOMS 50000
#define N_BONDS 100000
#define BATCH   16
#define N3      150000   // N_ATOMS*3
#define BK      32       // bucket capacity per atom (Poisson(4): P(deg>32) ~ 1e-15)

// ---- fast-path workspace layout (4-byte element offsets) ----
#define X_OFF    0            // 4096 floats
#define MC_OFF   4096         // 16 floats (M 9, c 3)
#define CNT_OFF  4112         // 50000 ints (4112*4 % 16 == 0)
#define BKT_OFF  54112        // 50000*32 = 1,600,000 ints
#define HA_OFF   1654112      // 2,400,000 floats
#define HB_OFF   4054112      // 2,400,000 floats
#define WS_FAST_BYTES ((size_t)(HB_OFF + 2400000) * 4)   // ~25.8 MB

// ---- fallback layout ----
#define DEGF_OFF 4112         // 50000 floats
#define HT_OFF   54144        // 2,400,000 floats
#define NB_OFF   2454144      // 2,400,000 floats (optional in ws)

// ================= shared device helpers =================

// tiny MLP for batch b; all 256 threads of the block participate.
__device__ __forceinline__ void mlp_block(int b, int j,
    const float* __restrict__ alpha,
    const float* __restrict__ w_in, const float* __restrict__ b_in,
    const float* __restrict__ w1a, const float* __restrict__ b1a,
    const float* __restrict__ w1b, const float* __restrict__ b1b,
    const float* __restrict__ w2a, const float* __restrict__ b2a,
    const float* __restrict__ w2b, const float* __restrict__ b2b,
    float* xs, float* ts, float* __restrict__ x_out)
{
    float v = fmaxf(w_in[j] * alpha[b] + b_in[j], 0.f);
    xs[j] = v;
    __syncthreads();

    float acc = b1a[j];
    const float4* wr = reinterpret_cast<const float4*>(w1a + j * 256);
    #pragma unroll 8
    for (int k4 = 0; k4 < 64; ++k4) {
        float4 w = wr[k4];
        acc += w.x * xs[4*k4] + w.y * xs[4*k4+1] + w.z * xs[4*k4+2] + w.w * xs[4*k4+3];
    }
    ts[j] = fmaxf(acc, 0.f);
    __syncthreads();

    acc = b1b[j] + xs[j];
    wr = reinterpret_cast<const float4*>(w1b + j * 256);
    #pragma unroll 8
    for (int k4 = 0; k4 < 64; ++k4) {
        float4 w = wr[k4];
        acc += w.x * ts[4*k4] + w.y * ts[4*k4+1] + w.z * ts[4*k4+2] + w.w * ts[4*k4+3];
    }
    v = fmaxf(acc, 0.f);
    __syncthreads();
    xs[j] = v;
    __syncthreads();

    acc = b2a[j];
    wr = reinterpret_cast<const float4*>(w2a + j * 256);
    #pragma unroll 8
    for (int k4 = 0; k4 < 64; ++k4) {
        float4 w = wr[k4];
        acc += w.x * xs[4*k4] + w.y * xs[4*k4+1] + w.z * xs[4*k4+2] + w.w * xs[4*k4+3];
    }
    ts[j] = fmaxf(acc, 0.f);
    __syncthreads();

    acc = b2b[j] + xs[j];
    wr = reinterpret_cast<const float4*>(w2b + j * 256);
    #pragma unroll 8
    for (int k4 = 0; k4 < 64; ++k4) {
        float4 w = wr[k4];
        acc += w.x * ts[4*k4] + w.y * ts[4*k4+1] + w.z * ts[4*k4+2] + w.w * ts[4*k4+3];
    }
    x_out[b * 256 + j] = fmaxf(acc, 0.f);
}

// ================= K1: prep (MLP + mc + transpose + cnt-zero) =================
// Transpose uses R7's proven mapping: coalesced WRITES to h, 12B scattered
// reads of pos (L2-absorbed). R8's read-coalesced variant regressed 15-20us.
struct PrepParams {
    const float *alpha, *pos;
    const float *w_in, *b_in, *w1a, *b1a, *w1b, *b1b, *w2a, *b2a, *w2b, *b2b;
    const float *msg_w, *msg_b, *upd_w, *upd_b;
    float *x, *mc;
    int *cnt;
    float *hA;
};

__global__ __launch_bounds__(256) void prep_kernel(PrepParams p)
{
    __shared__ float smem[512];
    const int bid = blockIdx.x, tid = threadIdx.x;
    const int nb = gridDim.x;

    if (bid < 16) {
        mlp_block(bid, tid, p.alpha, p.w_in, p.b_in,
                  p.w1a, p.b1a, p.w1b, p.b1b, p.w2a, p.b2a, p.w2b, p.b2b,
                  smem, smem + 256, p.x);
    } else if (bid == 16) {
        if (tid < 9) {
            int d = tid / 3, dp = tid % 3;
            float s = 0.f;
            for (int k = 0; k < 128; ++k) s += p.upd_w[d*128 + k] * p.msg_w[k*3 + dp];
            p.mc[tid] = s;
        } else if (tid < 12) {
            int d = tid - 9;
            float s = p.upd_b[d];
            for (int k = 0; k < 128; ++k) s += p.upd_w[d*128 + k] * p.msg_b[k];
            p.mc[9 + d] = s;
        }
    } else {
        const int i0 = (bid - 17) * 256 + tid;
        const int st = (nb - 17) * 256;
        if (i0 < N_ATOMS / 4)
            ((int4*)p.cnt)[i0] = make_int4(0, 0, 0, 0);
        for (int i = i0; i < N_ATOMS * 48; i += st) {
            int n = i / 48, c = i - n * 48;
            int b = c / 3, d = c - b * 3;
            p.hA[i] = p.pos[(b * N_ATOMS + n) * 3 + d];
        }
    }
}

// ================= K2: bucket fill (count + adjacency in one pass) =================
__global__ void fill_kernel(const int* __restrict__ bonds, int* __restrict__ cnt,
                            int* __restrict__ bucket)
{
    int e = blockIdx.x * blockDim.x + threadIdx.x;
    if (e >= N_BONDS) return;
    int a = bonds[2*e], b = bonds[2*e + 1];
    int sa = atomicAdd(cnt + a, 1);
    if (sa < BK) bucket[a * BK + sa] = b;
    int sb = atomicAdd(cnt + b, 1);
    if (sb < BK) bucket[b * BK + sb] = a;
}

// ============ K3/K4: bucket gather + mean + affine + residual ============
__global__ void gather_kernel(const int* __restrict__ cnt, const int* __restrict__ bucket,
                              const float* __restrict__ mc, const float* __restrict__ upd_b,
                              const float* __restrict__ h_in, float* __restrict__ h_out)
{
    int t = blockIdx.x * blockDim.x + threadIdx.x;
    if (t >= N_ATOMS * BATCH) return;
    int n = t >> 4, b = t & 15;
    int dg = cnt[n];
    int base = n * 48 + b * 3;
    float d0, d1, d2;
    if (dg > 0) {
        int m = dg > BK ? BK : dg;
        float s0 = 0.f, s1 = 0.f, s2 = 0.f;
        const int* bk = bucket + n * BK;
        for (int j = 0; j < m; ++j) {
            const float* hs = h_in + bk[j] * 48 + b * 3;
            s0 += hs[0]; s1 += hs[1]; s2 += hs[2];
        }
        float inv = 1.f / (float)dg;
        s0 *= inv; s1 *= inv; s2 *= inv;
        d0 = mc[9]  + mc[0]*s0 + mc[1]*s1 + mc[2]*s2;
        d1 = mc[10] + mc[3]*s0 + mc[4]*s1 + mc[5]*s2;
        d2 = mc[11] + mc[6]*s0 + mc[7]*s1 + mc[8]*s2;
    } else {
        d0 = upd_b[0]; d1 = upd_b[1]; d2 = upd_b[2];
    }
    h_out[base]     = h_in[base]     + d0;
    h_out[base + 1] = h_in[base + 1] + d1;
    h_out[base + 2] = h_in[base + 2] + d2;
}

// ---------------- K5: fused output GEMM + b_out + go-affine(h) ----------------
// 1 row/thread; full 256-float row = 4 chunks x 16 float4, double-buffered
// (16 loads in flight; 256 FMA/chunk ~ 512 cyc covers ~500 cyc L3 latency by
// ILP). 128-thr blocks (2 waves share 16KB xs), 1172 blocks = 9.2 waves/CU
// = 2.3 waves/SIMD of TLP on top. K-coverage invariant: 4 chunks x 16 = 64
// float4 = 256 floats (R12 bug: only 16 float4 were loaded).
__global__ __launch_bounds__(128) void out_kernel(
    const float* __restrict__ w_out, const float* __restrict__ b_out,
    const float* __restrict__ x, const float* __restrict__ h_t,
    const float* __restrict__ go_w, const float* __restrict__ go_b,
    float* __restrict__ out)
{
    __shared__ float4 xs[1024];                 // [b][k4], 16 KiB shared by 2 waves
    const int tid = threadIdx.x;
    const float4* xv = reinterpret_cast<const float4*>(x);
    #pragma unroll
    for (int i = 0; i < 8; ++i) xs[tid + i * 128] = xv[tid + i * 128];
    __syncthreads();

    const int r = blockIdx.x * 128 + tid;
    if (r >= N3) return;

    const float4* wr = reinterpret_cast<const float4*>(w_out + (size_t)r * 256);

    float acc[16];
    #pragma unroll
    for (int b = 0; b < 16; ++b) acc[b] = 0.f;

    float4 wbuf[16];
    #pragma unroll
    for (int i = 0; i < 16; ++i) wbuf[i] = wr[i];

    #pragma unroll 1
    for (int c = 0; c < 4; ++c) {
        float4 wcur[16];
        #pragma unroll
        for (int i = 0; i < 16; ++i) wcur[i] = wbuf[i];
        if (c < 3) {
            #pragma unroll
            for (int i = 0; i < 16; ++i) wbuf[i] = wr[(c + 1) * 16 + i];
        }
        #pragma unroll
        for (int i = 0; i < 16; ++i) {
            const int k4 = c * 16 + i;
            #pragma unroll
            for (int b = 0; b < 16; ++b) {
                float4 xf = xs[b * 64 + k4];
                acc[b] += wcur[i].x * xf.x + wcur[i].y * xf.y
                        + wcur[i].z * xf.z + wcur[i].w * xf.w;
            }
        }
    }

    const int n = r / 3, d = r - 3 * n;
    const float g0 = go_w[d*3], g1 = go_w[d*3 + 1], g2 = go_w[d*3 + 2];
    const float gb = go_b[d] + b_out[r];
    const float* hb = h_t + n * 48;
    #pragma unroll
    for (int b = 0; b < 16; ++b) {
        float g = gb + g0 * hb[b*3] + g1 * hb[b*3 + 1] + g2 * hb[b*3 + 2];
        out[(size_t)b * N3 + r] = acc[b] + g;
    }
}

// ================= fallback (small-ws) kernels: atomic scatter path =================
__global__ void zero4_kernel(int4* __restrict__ p, int n4)
{
    int t = blockIdx.x * 256 + threadIdx.x;
    if (t < n4) p[t] = make_int4(0, 0, 0, 0);
}

__global__ void mlp_head_kernel(const float* __restrict__ alpha,
    const float* __restrict__ w_in, const float* __restrict__ b_in,
    const float* __restrict__ w1a, const float* __restrict__ b1a,
    const float* __restrict__ w1b, const float* __restrict__ b1b,
    const float* __restrict__ w2a, const float* __restrict__ b2a,
    const float* __restrict__ w2b, const float* __restrict__ b2b,
    const float* __restrict__ msg_w, const float* __restrict__ msg_b,
    const float* __restrict__ upd_w, const float* __restrict__ upd_b,
    float* __restrict__ x_out, float* __restrict__ mc)
{
    const int b = blockIdx.x, j = threadIdx.x;
    if (b == 16) {
        if (j < 9) {
            int d = j / 3, dp = j % 3;
            float s = 0.f;
            for (int k = 0; k < 128; ++k) s += upd_w[d*128 + k] * msg_w[k*3 + dp];
            mc[j] = s;
        } else if (j < 12) {
            int d = j - 9;
            float s = upd_b[d];
            for (int k = 0; k < 128; ++k) s += upd_w[d*128 + k] * msg_b[k];
            mc[9 + d] = s;
        }
        return;
    }
    __shared__ float xs[256];
    __shared__ float ts[256];
    mlp_block(b, j, alpha, w_in, b_in, w1a, b1a, w1b, b1b, w2a, b2a, w2b, b2b,
              xs, ts, x_out);
}

__global__ void transpose_in_kernel(const float* __restrict__ pos, float* __restrict__ h_t)
{
    int t = blockIdx.x * blockDim.x + threadIdx.x;
    if (t >= N_ATOMS * 48) return;
    int n = t / 48, c = t % 48;
    int b = c / 3, d = c % 3;
    h_t[t] = pos[(b * N_ATOMS + n) * 3 + d];
}

__global__ void degf_kernel(const int* __restrict__ bonds, float* __restrict__ deg)
{
    int e = blockIdx.x * blockDim.x + threadIdx.x;
    if (e >= N_BONDS) return;
    atomicAdd(deg + bonds[2*e],     1.f);
    atomicAdd(deg + bonds[2*e + 1], 1.f);
}

__global__ void scatter_kernel(const int* __restrict__ bonds,
                               const float* __restrict__ h_t, float* __restrict__ nb_t)
{
    int t = blockIdx.x * 192 + threadIdx.x;
    int e = t / 48, c = t % 48;
    if (e >= N_BONDS) return;
    int a  = bonds[2*e];
    int bb = bonds[2*e + 1];
    float va = h_t[a  * 48 + c];
    float vb = h_t[bb * 48 + c];
    atomicAdd(nb_t + bb * 48 + c, va);
    atomicAdd(nb_t + a  * 48 + c, vb);
}

__global__ void update_kernel(const float* __restrict__ nb_t, const float* __restrict__ deg,
                              const float* __restrict__ mc, const float* __restrict__ upd_b,
                              float* __restrict__ h_t)
{
    int t = blockIdx.x * blockDim.x + threadIdx.x;
    if (t >= N_ATOMS * BATCH) return;
    int n = t >> 4;
    int base = n * 48 + (t & 15) * 3;
    float dg = deg[n];
    float d0, d1, d2;
    if (dg > 0.f) {
        float inv = 1.f / dg;
        float m0 = nb_t[base] * inv, m1 = nb_t[base+1] * inv, m2 = nb_t[base+2] * inv;
        d0 = mc[9]  + mc[0]*m0 + mc[1]*m1 + mc[2]*m2;
        d1 = mc[10] + mc[3]*m0 + mc[4]*m1 + mc[5]*m2;
        d2 = mc[11] + mc[6]*m0 + mc[7]*m1 + mc[8]*m2;
    } else {
        d0 = upd_b[0]; d1 = upd_b[1]; d2 = upd_b[2];
    }
    h_t[base]     += d0;
    h_t[base + 1] += d1;
    h_t[base + 2] += d2;
}

extern "C" void kernel_launch(void* const* d_in, const int* in_sizes, int n_in,
                              void* d_out, int out_size, void* d_ws, size_t ws_size,
                              hipStream_t stream)
{
    const float* alpha = (const float*)d_in[0];
    const float* pos   = (const float*)d_in[1];
    const int*   bonds = (const int*)  d_in[2];
    const float* w_in  = (const float*)d_in[3];
    const float* b_in  = (const float*)d_in[4];
    const float* w1a   = (const float*)d_in[5];
    const float* b1a   = (const float*)d_in[6];
    const float* w1b   = (const float*)d_in[7];
    const float* b1b   = (const float*)d_in[8];
    const float* w2a   = (const float*)d_in[9];
    const float* b2a   = (const float*)d_in[10];
    const float* w2b   = (const float*)d_in[11];
    const float* b2b   = (const float*)d_in[12];
    const float* w_out = (const float*)d_in[13];
    const float* b_out = (const float*)d_in[14];
    const float* msg_w = (const float*)d_in[15];
    const float* msg_b = (const float*)d_in[16];
    const float* upd_w = (const float*)d_in[17];
    const float* upd_b = (const float*)d_in[18];
    const float* go_w  = (const float*)d_in[19];
    const float* go_b  = (const float*)d_in[20];

    float* out = (float*)d_out;
    float* ws  = (float*)d_ws;
    float* x   = ws + X_OFF;
    float* mc  = ws + MC_OFF;

    float* h_final;
    if (ws_size >= WS_FAST_BYTES) {
        // -------- 5-dispatch full-occupancy fast path --------
        PrepParams pp;
        pp.alpha = alpha; pp.pos = pos;
        pp.w_in = w_in; pp.b_in = b_in;
        pp.w1a = w1a; pp.b1a = b1a; pp.w1b = w1b; pp.b1b = b1b;
        pp.w2a = w2a; pp.b2a = b2a; pp.w2b = w2b; pp.b2b = b2b;
        pp.msg_w = msg_w; pp.msg_b = msg_b; pp.upd_w = upd_w; pp.upd_b = upd_b;
        pp.x = x; pp.mc = mc;
        pp.cnt = (int*)(ws + CNT_OFF);
        pp.hA  = ws + HA_OFF;
        prep_kernel<<<1024, 256, 0, stream>>>(pp);

        int* cnt    = (int*)(ws + CNT_OFF);
        int* bucket = (int*)(ws + BKT_OFF);
        float* hA   = ws + HA_OFF;
        float* hB   = ws + HB_OFF;

        fill_kernel<<<(N_BONDS + 255) / 256, 256, 0, stream>>>(bonds, cnt, bucket);
        gather_kernel<<<(N_ATOMS * BATCH + 255) / 256, 256, 0, stream>>>(cnt, bucket, mc, upd_b, hA, hB);
        gather_kernel<<<(N_ATOMS * BATCH + 255) / 256, 256, 0, stream>>>(cnt, bucket, mc, upd_b, hB, hA);
        h_final = hA;
    } else {
        // -------- fallback: multi-dispatch atomic scatter path --------
        float* degf = ws + DEGF_OFF;
        float* h_t  = ws + HT_OFF;
        size_t need_full = (size_t)(NB_OFF + N_ATOMS * 48) * sizeof(float);
        float* nb_t = (ws_size >= need_full) ? (ws + NB_OFF) : out;

        mlp_head_kernel<<<17, 256, 0, stream>>>(alpha, w_in, b_in,
                                                w1a, b1a, w1b, b1b,
                                                w2a, b2a, w2b, b2b,
                                                msg_w, msg_b, upd_w, upd_b, x, mc);
        zero4_kernel<<<(N_ATOMS / 4 + 255) / 256, 256, 0, stream>>>((int4*)degf, N_ATOMS / 4);
        degf_kernel<<<(N_BONDS + 255) / 256, 256, 0, stream>>>(bonds, degf);
        transpose_in_kernel<<<(N_ATOMS * 48 + 255) / 256, 256, 0, stream>>>(pos, h_t);
        for (int it = 0; it < 2; ++it) {
            zero4_kernel<<<(N_ATOMS * 48 / 4 + 255) / 256, 256, 0, stream>>>((int4*)nb_t, N_ATOMS * 48 / 4);
            scatter_kernel<<<25000, 192, 0, stream>>>(bonds, h_t, nb_t);
            update_kernel<<<(N_ATOMS * BATCH + 255) / 256, 256, 0, stream>>>(nb_t, degf, mc, upd_b, h_t);
        }
        h_final = h_t;
    }

    // 1172 blocks x 128 threads; 1 row/thread, 4x16-float4 double-buffered
    out_kernel<<<(N3 + 127) / 128, 128, 0, stream>>>(w_out, b_out, x, h_final, go_w, go_b, out);
}

// Round 14
// 116.563 us; speedup vs baseline: 1.4700x; 1.1421x over previous
//
#include <hip/hip_runtime.h>

#define N_ATOMS 50000
#define N_BONDS 100000
#define BATCH   16
#define N3      150000   // N_ATOMS*3
#define BK      32       // bucket capacity per atom (Poisson(4): P(deg>32) ~ 1e-15)

// ---- fast-path workspace layout (4-byte element offsets) ----
#define X_OFF    0            // 4096 floats
#define MC_OFF   4096         // 16 floats (M 9, c 3)
#define CNT_OFF  4112         // 50000 ints (4112*4 % 16 == 0)
#define BKT_OFF  54112        // 50000*32 = 1,600,000 ints
#define HA_OFF   1654112      // 2,400,000 floats
#define HB_OFF   4054112      // 2,400,000 floats
#define WS_FAST_BYTES ((size_t)(HB_OFF + 2400000) * 4)   // ~25.8 MB

// ---- fallback layout ----
#define DEGF_OFF 4112         // 50000 floats
#define HT_OFF   54144        // 2,400,000 floats
#define NB_OFF   2454144      // 2,400,000 floats (optional in ws)

typedef __bf16 bf16x8 __attribute__((ext_vector_type(8)));
typedef float  f32x4  __attribute__((ext_vector_type(4)));

// ================= shared device helpers =================

// tiny MLP for batch b; all 256 threads of the block participate.
__device__ __forceinline__ void mlp_block(int b, int j,
    const float* __restrict__ alpha,
    const float* __restrict__ w_in, const float* __restrict__ b_in,
    const float* __restrict__ w1a, const float* __restrict__ b1a,
    const float* __restrict__ w1b, const float* __restrict__ b1b,
    const float* __restrict__ w2a, const float* __restrict__ b2a,
    const float* __restrict__ w2b, const float* __restrict__ b2b,
    float* xs, float* ts, float* __restrict__ x_out)
{
    float v = fmaxf(w_in[j] * alpha[b] + b_in[j], 0.f);
    xs[j] = v;
    __syncthreads();

    float acc = b1a[j];
    const float4* wr = reinterpret_cast<const float4*>(w1a + j * 256);
    #pragma unroll 8
    for (int k4 = 0; k4 < 64; ++k4) {
        float4 w = wr[k4];
        acc += w.x * xs[4*k4] + w.y * xs[4*k4+1] + w.z * xs[4*k4+2] + w.w * xs[4*k4+3];
    }
    ts[j] = fmaxf(acc, 0.f);
    __syncthreads();

    acc = b1b[j] + xs[j];
    wr = reinterpret_cast<const float4*>(w1b + j * 256);
    #pragma unroll 8
    for (int k4 = 0; k4 < 64; ++k4) {
        float4 w = wr[k4];
        acc += w.x * ts[4*k4] + w.y * ts[4*k4+1] + w.z * ts[4*k4+2] + w.w * ts[4*k4+3];
    }
    v = fmaxf(acc, 0.f);
    __syncthreads();
    xs[j] = v;
    __syncthreads();

    acc = b2a[j];
    wr = reinterpret_cast<const float4*>(w2a + j * 256);
    #pragma unroll 8
    for (int k4 = 0; k4 < 64; ++k4) {
        float4 w = wr[k4];
        acc += w.x * xs[4*k4] + w.y * xs[4*k4+1] + w.z * xs[4*k4+2] + w.w * xs[4*k4+3];
    }
    ts[j] = fmaxf(acc, 0.f);
    __syncthreads();

    acc = b2b[j] + xs[j];
    wr = reinterpret_cast<const float4*>(w2b + j * 256);
    #pragma unroll 8
    for (int k4 = 0; k4 < 64; ++k4) {
        float4 w = wr[k4];
        acc += w.x * ts[4*k4] + w.y * ts[4*k4+1] + w.z * ts[4*k4+2] + w.w * ts[4*k4+3];
    }
    x_out[b * 256 + j] = fmaxf(acc, 0.f);
}

// ================= K1: prep (MLP + mc + transpose + cnt-zero) =================
// Transpose keeps R7's proven mapping: coalesced WRITES to h, 12B scattered
// reads of pos (L2-absorbed). R8's read-coalesced variant regressed 15-20us.
struct PrepParams {
    const float *alpha, *pos;
    const float *w_in, *b_in, *w1a, *b1a, *w1b, *b1b, *w2a, *b2a, *w2b, *b2b;
    const float *msg_w, *msg_b, *upd_w, *upd_b;
    float *x, *mc;
    int *cnt;
    float *hA;
};

__global__ __launch_bounds__(256) void prep_kernel(PrepParams p)
{
    __shared__ float smem[512];
    const int bid = blockIdx.x, tid = threadIdx.x;
    const int nb = gridDim.x;

    if (bid < 16) {
        mlp_block(bid, tid, p.alpha, p.w_in, p.b_in,
                  p.w1a, p.b1a, p.w1b, p.b1b, p.w2a, p.b2a, p.w2b, p.b2b,
                  smem, smem + 256, p.x);
    } else if (bid == 16) {
        if (tid < 9) {
            int d = tid / 3, dp = tid % 3;
            float s = 0.f;
            for (int k = 0; k < 128; ++k) s += p.upd_w[d*128 + k] * p.msg_w[k*3 + dp];
            p.mc[tid] = s;
        } else if (tid < 12) {
            int d = tid - 9;
            float s = p.upd_b[d];
            for (int k = 0; k < 128; ++k) s += p.upd_w[d*128 + k] * p.msg_b[k];
            p.mc[9 + d] = s;
        }
    } else {
        const int i0 = (bid - 17) * 256 + tid;
        const int st = (nb - 17) * 256;
        if (i0 < N_ATOMS / 4)
            ((int4*)p.cnt)[i0] = make_int4(0, 0, 0, 0);
        for (int i = i0; i < N_ATOMS * 48; i += st) {
            int n = i / 48, c = i - n * 48;
            int b = c / 3, d = c - b * 3;
            p.hA[i] = p.pos[(b * N_ATOMS + n) * 3 + d];
        }
    }
}

// ================= K2: bucket fill (count + adjacency in one pass) =================
__global__ void fill_kernel(const int* __restrict__ bonds, int* __restrict__ cnt,
                            int* __restrict__ bucket)
{
    int e = blockIdx.x * blockDim.x + threadIdx.x;
    if (e >= N_BONDS) return;
    int a = bonds[2*e], b = bonds[2*e + 1];
    int sa = atomicAdd(cnt + a, 1);
    if (sa < BK) bucket[a * BK + sa] = b;
    int sb = atomicAdd(cnt + b, 1);
    if (sb < BK) bucket[b * BK + sb] = a;
}

// ============ K3/K4: bucket gather + mean + affine + residual ============
__global__ void gather_kernel(const int* __restrict__ cnt, const int* __restrict__ bucket,
                              const float* __restrict__ mc, const float* __restrict__ upd_b,
                              const float* __restrict__ h_in, float* __restrict__ h_out)
{
    int t = blockIdx.x * blockDim.x + threadIdx.x;
    if (t >= N_ATOMS * BATCH) return;
    int n = t >> 4, b = t & 15;
    int dg = cnt[n];
    int base = n * 48 + b * 3;
    float d0, d1, d2;
    if (dg > 0) {
        int m = dg > BK ? BK : dg;
        float s0 = 0.f, s1 = 0.f, s2 = 0.f;
        const int* bk = bucket + n * BK;
        for (int j = 0; j < m; ++j) {
            const float* hs = h_in + bk[j] * 48 + b * 3;
            s0 += hs[0]; s1 += hs[1]; s2 += hs[2];
        }
        float inv = 1.f / (float)dg;
        s0 *= inv; s1 *= inv; s2 *= inv;
        d0 = mc[9]  + mc[0]*s0 + mc[1]*s1 + mc[2]*s2;
        d1 = mc[10] + mc[3]*s0 + mc[4]*s1 + mc[5]*s2;
        d2 = mc[11] + mc[6]*s0 + mc[7]*s1 + mc[8]*s2;
    } else {
        d0 = upd_b[0]; d1 = upd_b[1]; d2 = upd_b[2];
    }
    h_out[base]     = h_in[base]     + d0;
    h_out[base + 1] = h_in[base + 1] + d1;
    h_out[base + 2] = h_in[base + 2] + d2;
}

// ---------------- K5: MFMA output GEMM + b_out + go-affine(h) ----------------
// C[16 batch, 150000 rows] = X[16,256] @ W^T via mfma_f32_16x16x32_bf16.
// fp32 -> bf16 conversion happens IN REGISTERS (no extra pass; traffic stays
// 154MB; fp32 accumulate). A-frag: m = lane&15 = batch, 8 consecutive k.
// B-frag: n = lane&15 = w row, SAME consecutive-8 k scheme -> k-permutation
// invariance makes the exact hw k-map irrelevant (A and B match slot-wise).
// C/D (m89-verified): r = r0 + (lane&15), batch = (lane>>4)*4 + reg.
// 8 MFMA/tile replaces 4096 VALU FMAs; 16 loads in flight per tile.
__global__ __launch_bounds__(256) void out_kernel(
    const float* __restrict__ w_out, const float* __restrict__ b_out,
    const float* __restrict__ x, const float* __restrict__ h_t,
    const float* __restrict__ go_w, const float* __restrict__ go_b,
    float* __restrict__ out)
{
    const int lane = threadIdx.x & 63;
    const int widx = threadIdx.x >> 6;
    const int wave = blockIdx.x * 4 + widx;   // 0..2343
    const int g  = lane >> 4;                 // k-group 0..3
    const int mn = lane & 15;                 // m(batch) for A, n(row) for B

    // A fragments once per wave: x[mn][kb*32 + g*8 + 0..7] as bf16x8
    bf16x8 afrag[8];
    const float* xrow = x + mn * 256 + g * 8;
    #pragma unroll
    for (int kb = 0; kb < 8; ++kb) {
        float4 lo = *reinterpret_cast<const float4*>(xrow + kb * 32);
        float4 hi = *reinterpret_cast<const float4*>(xrow + kb * 32 + 4);
        bf16x8 a;
        a[0] = (__bf16)lo.x; a[1] = (__bf16)lo.y; a[2] = (__bf16)lo.z; a[3] = (__bf16)lo.w;
        a[4] = (__bf16)hi.x; a[5] = (__bf16)hi.y; a[6] = (__bf16)hi.z; a[7] = (__bf16)hi.w;
        afrag[kb] = a;
    }

    #pragma unroll 1
    for (int t = 0; t < 4; ++t) {
        const int tile = wave * 4 + t;        // 9375 tiles of 16 rows
        if (tile >= 9375) break;
        const int r = tile * 16 + mn;
        const float* wrow = w_out + (size_t)r * 256 + g * 8;

        f32x4 acc = {0.f, 0.f, 0.f, 0.f};
        #pragma unroll
        for (int kb = 0; kb < 8; ++kb) {
            float4 lo = *reinterpret_cast<const float4*>(wrow + kb * 32);
            float4 hi = *reinterpret_cast<const float4*>(wrow + kb * 32 + 4);
            bf16x8 bfr;
            bfr[0] = (__bf16)lo.x; bfr[1] = (__bf16)lo.y; bfr[2] = (__bf16)lo.z; bfr[3] = (__bf16)lo.w;
            bfr[4] = (__bf16)hi.x; bfr[5] = (__bf16)hi.y; bfr[6] = (__bf16)hi.z; bfr[7] = (__bf16)hi.w;
            acc = __builtin_amdgcn_mfma_f32_16x16x32_bf16(afrag[kb], bfr, acc, 0, 0, 0);
        }

        const int n = r / 3, d = r - 3 * n;
        const float g0 = go_w[d*3], g1 = go_w[d*3 + 1], g2 = go_w[d*3 + 2];
        const float gb = go_b[d] + b_out[r];
        #pragma unroll
        for (int j = 0; j < 4; ++j) {
            const int b = g * 4 + j;          // batch = (lane>>4)*4 + reg
            const float* hb = h_t + n * 48 + b * 3;
            float gaff = gb + g0 * hb[0] + g1 * hb[1] + g2 * hb[2];
            out[(size_t)b * N3 + r] = acc[j] + gaff;
        }
    }
}

// ================= fallback (small-ws) kernels: atomic scatter path =================
__global__ void zero4_kernel(int4* __restrict__ p, int n4)
{
    int t = blockIdx.x * 256 + threadIdx.x;
    if (t < n4) p[t] = make_int4(0, 0, 0, 0);
}

__global__ void mlp_head_kernel(const float* __restrict__ alpha,
    const float* __restrict__ w_in, const float* __restrict__ b_in,
    const float* __restrict__ w1a, const float* __restrict__ b1a,
    const float* __restrict__ w1b, const float* __restrict__ b1b,
    const float* __restrict__ w2a, const float* __restrict__ b2a,
    const float* __restrict__ w2b, const float* __restrict__ b2b,
    const float* __restrict__ msg_w, const float* __restrict__ msg_b,
    const float* __restrict__ upd_w, const float* __restrict__ upd_b,
    float* __restrict__ x_out, float* __restrict__ mc)
{
    const int b = blockIdx.x, j = threadIdx.x;
    if (b == 16) {
        if (j < 9) {
            int d = j / 3, dp = j % 3;
            float s = 0.f;
            for (int k = 0; k < 128; ++k) s += upd_w[d*128 + k] * msg_w[k*3 + dp];
            mc[j] = s;
        } else if (j < 12) {
            int d = j - 9;
            float s = upd_b[d];
            for (int k = 0; k < 128; ++k) s += upd_w[d*128 + k] * msg_b[k];
            mc[9 + d] = s;
        }
        return;
    }
    __shared__ float xs[256];
    __shared__ float ts[256];
    mlp_block(b, j, alpha, w_in, b_in, w1a, b1a, w1b, b1b, w2a, b2a, w2b, b2b,
              xs, ts, x_out);
}

__global__ void transpose_in_kernel(const float* __restrict__ pos, float* __restrict__ h_t)
{
    int t = blockIdx.x * blockDim.x + threadIdx.x;
    if (t >= N_ATOMS * 48) return;
    int n = t / 48, c = t % 48;
    int b = c / 3, d = c % 3;
    h_t[t] = pos[(b * N_ATOMS + n) * 3 + d];
}

__global__ void degf_kernel(const int* __restrict__ bonds, float* __restrict__ deg)
{
    int e = blockIdx.x * blockDim.x + threadIdx.x;
    if (e >= N_BONDS) return;
    atomicAdd(deg + bonds[2*e],     1.f);
    atomicAdd(deg + bonds[2*e + 1], 1.f);
}

__global__ void scatter_kernel(const int* __restrict__ bonds,
                               const float* __restrict__ h_t, float* __restrict__ nb_t)
{
    int t = blockIdx.x * 192 + threadIdx.x;
    int e = t / 48, c = t % 48;
    if (e >= N_BONDS) return;
    int a  = bonds[2*e];
    int bb = bonds[2*e + 1];
    float va = h_t[a  * 48 + c];
    float vb = h_t[bb * 48 + c];
    atomicAdd(nb_t + bb * 48 + c, va);
    atomicAdd(nb_t + a  * 48 + c, vb);
}

__global__ void update_kernel(const float* __restrict__ nb_t, const float* __restrict__ deg,
                              const float* __restrict__ mc, const float* __restrict__ upd_b,
                              float* __restrict__ h_t)
{
    int t = blockIdx.x * blockDim.x + threadIdx.x;
    if (t >= N_ATOMS * BATCH) return;
    int n = t >> 4;
    int base = n * 48 + (t & 15) * 3;
    float dg = deg[n];
    float d0, d1, d2;
    if (dg > 0.f) {
        float inv = 1.f / dg;
        float m0 = nb_t[base] * inv, m1 = nb_t[base+1] * inv, m2 = nb_t[base+2] * inv;
        d0 = mc[9]  + mc[0]*m0 + mc[1]*m1 + mc[2]*m2;
        d1 = mc[10] + mc[3]*m0 + mc[4]*m1 + mc[5]*m2;
        d2 = mc[11] + mc[6]*m0 + mc[7]*m1 + mc[8]*m2;
    } else {
        d0 = upd_b[0]; d1 = upd_b[1]; d2 = upd_b[2];
    }
    h_t[base]     += d0;
    h_t[base + 1] += d1;
    h_t[base + 2] += d2;
}

extern "C" void kernel_launch(void* const* d_in, const int* in_sizes, int n_in,
                              void* d_out, int out_size, void* d_ws, size_t ws_size,
                              hipStream_t stream)
{
    const float* alpha = (const float*)d_in[0];
    const float* pos   = (const float*)d_in[1];
    const int*   bonds = (const int*)  d_in[2];
    const float* w_in  = (const float*)d_in[3];
    const float* b_in  = (const float*)d_in[4];
    const float* w1a   = (const float*)d_in[5];
    const float* b1a   = (const float*)d_in[6];
    const float* w1b   = (const float*)d_in[7];
    const float* b1b   = (const float*)d_in[8];
    const float* w2a   = (const float*)d_in[9];
    const float* b2a   = (const float*)d_in[10];
    const float* w2b   = (const float*)d_in[11];
    const float* b2b   = (const float*)d_in[12];
    const float* w_out = (const float*)d_in[13];
    const float* b_out = (const float*)d_in[14];
    const float* msg_w = (const float*)d_in[15];
    const float* msg_b = (const float*)d_in[16];
    const float* upd_w = (const float*)d_in[17];
    const float* upd_b = (const float*)d_in[18];
    const float* go_w  = (const float*)d_in[19];
    const float* go_b  = (const float*)d_in[20];

    float* out = (float*)d_out;
    float* ws  = (float*)d_ws;
    float* x   = ws + X_OFF;
    float* mc  = ws + MC_OFF;

    float* h_final;
    if (ws_size >= WS_FAST_BYTES) {
        // -------- 5-dispatch full-occupancy fast path --------
        PrepParams pp;
        pp.alpha = alpha; pp.pos = pos;
        pp.w_in = w_in; pp.b_in = b_in;
        pp.w1a = w1a; pp.b1a = b1a; pp.w1b = w1b; pp.b1b = b1b;
        pp.w2a = w2a; pp.b2a = b2a; pp.w2b = w2b; pp.b2b = b2b;
        pp.msg_w = msg_w; pp.msg_b = msg_b; pp.upd_w = upd_w; pp.upd_b = upd_b;
        pp.x = x; pp.mc = mc;
        pp.cnt = (int*)(ws + CNT_OFF);
        pp.hA  = ws + HA_OFF;
        prep_kernel<<<1024, 256, 0, stream>>>(pp);

        int* cnt    = (int*)(ws + CNT_OFF);
        int* bucket = (int*)(ws + BKT_OFF);
        float* hA   = ws + HA_OFF;
        float* hB   = ws + HB_OFF;

        fill_kernel<<<(N_BONDS + 255) / 256, 256, 0, stream>>>(bonds, cnt, bucket);
        gather_kernel<<<(N_ATOMS * BATCH + 255) / 256, 256, 0, stream>>>(cnt, bucket, mc, upd_b, hA, hB);
        gather_kernel<<<(N_ATOMS * BATCH + 255) / 256, 256, 0, stream>>>(cnt, bucket, mc, upd_b, hB, hA);
        h_final = hA;
    } else {
        // -------- fallback: multi-dispatch atomic scatter path --------
        float* degf = ws + DEGF_OFF;
        float* h_t  = ws + HT_OFF;
        size_t need_full = (size_t)(NB_OFF + N_ATOMS * 48) * sizeof(float);
        float* nb_t = (ws_size >= need_full) ? (ws + NB_OFF) : out;

        mlp_head_kernel<<<17, 256, 0, stream>>>(alpha, w_in, b_in,
                                                w1a, b1a, w1b, b1b,
                                                w2a, b2a, w2b, b2b,
                                                msg_w, msg_b, upd_w, upd_b, x, mc);
        zero4_kernel<<<(N_ATOMS / 4 + 255) / 256, 256, 0, stream>>>((int4*)degf, N_ATOMS / 4);
        degf_kernel<<<(N_BONDS + 255) / 256, 256, 0, stream>>>(bonds, degf);
        transpose_in_kernel<<<(N_ATOMS * 48 + 255) / 256, 256, 0, stream>>>(pos, h_t);
        for (int it = 0; it < 2; ++it) {
            zero4_kernel<<<(N_ATOMS * 48 / 4 + 255) / 256, 256, 0, stream>>>((int4*)nb_t, N_ATOMS * 48 / 4);
            scatter_kernel<<<25000, 192, 0, stream>>>(bonds, h_t, nb_t);
            update_kernel<<<(N_ATOMS * BATCH + 255) / 256, 256, 0, stream>>>(nb_t, degf, mc, upd_b, h_t);
        }
        h_final = h_t;
    }

    // MFMA GEMM: 586 blocks x 4 waves, 4 tiles (64 rows) per wave
    out_kernel<<<586, 256, 0, stream>>>(w_out, b_out, x, h_final, go_w, go_b, out);
}